// Round 1
// baseline (21885.709 us; speedup 1.0000x reference)
//
#include <hip/hip_runtime.h>
#include <hip/hip_bf16.h>

// LSTM: T=2048 steps, B=64 batch, D=512 in, H=512 hidden.
// Persistent-kernel design: 64 blocks x 256 threads, block b owns hidden cols
// [8b, 8b+8) -> 32 gate columns. W slice stays in LDS (bf16, swizzled) for the
// whole run; c-state stays in registers; h is exchanged every step through a
// 2-slot bf16 ring buffer in d_ws using agent-scope atomics + a global
// atomic-counter barrier (one per step).

#define T_N 2048
#define B_N 64
#define D_N 512
#define H_N 512
#define DH_N 1024
#define NBLK 64
#define CPB 8
#define GCPB 32
#define NTHR 256

#define STACK_ELEMS ((size_t)T_N * B_N * H_N)   // 67108864
#define HT_OFF STACK_ELEMS
#define CT_OFF (STACK_ELEMS + (size_t)B_N * H_N)

typedef __attribute__((ext_vector_type(4))) float f32x4;
typedef __attribute__((ext_vector_type(8))) short bf16x8;

__device__ __forceinline__ unsigned short f2bf(float f) {
  __hip_bfloat16 h = __float2bfloat16(f);
  union { __hip_bfloat16 h; unsigned short u; } u;
  u.h = h;
  return u.u;
}

__device__ __forceinline__ float sigf(float x) { return 1.0f / (1.0f + __expf(-x)); }
__device__ __forceinline__ float tanhfast(float x) { return 1.0f - 2.0f / (__expf(2.0f * x) + 1.0f); }

__global__ void init_ws_kernel(unsigned* cnt, unsigned* ring32) {
  int i = blockIdx.x * blockDim.x + threadIdx.x;
  if (i == 0) *cnt = 0u;
  if (i < (2 * B_N * H_N) / 2) ring32[i] = 0u;  // zero both ring slots (32768 u32)
}

__global__ void xconv_kernel(const float* __restrict__ X, unsigned short* __restrict__ Xb) {
  size_t i = ((size_t)blockIdx.x * blockDim.x + threadIdx.x) * 8;
  float4 v0 = *(const float4*)(X + i);
  float4 v1 = *(const float4*)(X + i + 4);
  bf16x8 o;
  o[0] = (short)f2bf(v0.x); o[1] = (short)f2bf(v0.y);
  o[2] = (short)f2bf(v0.z); o[3] = (short)f2bf(v0.w);
  o[4] = (short)f2bf(v1.x); o[5] = (short)f2bf(v1.y);
  o[6] = (short)f2bf(v1.z); o[7] = (short)f2bf(v1.w);
  *(bf16x8*)(Xb + i) = o;
}

__global__ __launch_bounds__(NTHR, 1) void lstm_kernel(
    const float* __restrict__ X, const unsigned short* __restrict__ Xb,
    const float* __restrict__ Wf, const float* __restrict__ bF,
    const float* __restrict__ Wi, const float* __restrict__ bI,
    const float* __restrict__ Wg, const float* __restrict__ bG,
    const float* __restrict__ Wo, const float* __restrict__ bO,
    unsigned short* __restrict__ ring, unsigned* __restrict__ cnt,
    float* __restrict__ out) {
  // W slice in LDS: 32 gate-cols x 1024 k, bf16, k XOR-swizzled per col.
  __shared__ unsigned short Wl[GCPB * DH_N];  // 64 KB

  const int tid = threadIdx.x;
  const int blk = blockIdx.x;
  const int c0 = blk * CPB;
  const int w = tid >> 6;        // wave 0..3 -> A-rows 16w..16w+15
  const int lane = tid & 63;
  const int l16 = lane & 15;
  const int g16 = lane >> 4;

  // Stage W (cols: 0-7=f, 8-15=i, 16-23=g, 24-31=o)
  for (int idx = tid; idx < GCPB * DH_N; idx += NTHR) {
    int k = idx >> 5;
    int cl = idx & 31;
    const float* wsrc = (cl < 8) ? Wf : (cl < 16) ? Wi : (cl < 24) ? Wg : Wo;
    float v = wsrc[(size_t)k * H_N + c0 + (cl & 7)];
    Wl[cl * DH_N + (k ^ ((cl & 7) << 3))] = f2bf(v);
  }

  const int cc = l16 & 7;
  const float bias0 = (l16 < 8) ? bF[c0 + cc] : bI[c0 + cc];
  const float bias1 = (l16 < 8) ? bG[c0 + cc] : bO[c0 + cc];
  __syncthreads();

  const int arow = 16 * w + l16;  // A row this lane feeds into mfma
  const int kg = 8 * g16;         // k sub-offset within a 32-wide K step
  const int bofs0 = l16 * DH_N;          // N-tile 0: col l16
  const int bofs1 = (16 + l16) * DH_N;   // N-tile 1: col 16+l16
  const int swz = (l16 & 7) << 3;        // same swizzle for both (cols share low 3 bits)

  float cst[4] = {0.f, 0.f, 0.f, 0.f};
  float hT_local[4] = {0.f, 0.f, 0.f, 0.f};

  for (int t = 0; t < T_N; ++t) {
    const int slotR = (t + 1) & 1;  // holds h_{t-1}
    const int slotW = t & 1;        // receives h_t
    f32x4 acc0 = {0.f, 0.f, 0.f, 0.f};
    f32x4 acc1 = {0.f, 0.f, 0.f, 0.f};

    // ---- x contribution (k = 0..511), no recurrence dependence
    if (Xb) {
      const unsigned short* xp = Xb + ((size_t)t * B_N + arow) * D_N + kg;
#pragma unroll 4
      for (int kk = 0; kk < 16; ++kk) {
        bf16x8 a = *(const bf16x8*)(xp + kk * 32);
        int kb = kk * 32 + kg;
        bf16x8 b0 = *(const bf16x8*)&Wl[bofs0 + (kb ^ swz)];
        bf16x8 b1 = *(const bf16x8*)&Wl[bofs1 + (kb ^ swz)];
        acc0 = __builtin_amdgcn_mfma_f32_16x16x32_bf16(a, b0, acc0, 0, 0, 0);
        acc1 = __builtin_amdgcn_mfma_f32_16x16x32_bf16(a, b1, acc1, 0, 0, 0);
      }
    } else {
      const float* xp = X + ((size_t)t * B_N + arow) * D_N + kg;
#pragma unroll 2
      for (int kk = 0; kk < 16; ++kk) {
        float4 v0 = *(const float4*)(xp + kk * 32);
        float4 v1 = *(const float4*)(xp + kk * 32 + 4);
        bf16x8 a;
        a[0] = (short)f2bf(v0.x); a[1] = (short)f2bf(v0.y);
        a[2] = (short)f2bf(v0.z); a[3] = (short)f2bf(v0.w);
        a[4] = (short)f2bf(v1.x); a[5] = (short)f2bf(v1.y);
        a[6] = (short)f2bf(v1.z); a[7] = (short)f2bf(v1.w);
        int kb = kk * 32 + kg;
        bf16x8 b0 = *(const bf16x8*)&Wl[bofs0 + (kb ^ swz)];
        bf16x8 b1 = *(const bf16x8*)&Wl[bofs1 + (kb ^ swz)];
        acc0 = __builtin_amdgcn_mfma_f32_16x16x32_bf16(a, b0, acc0, 0, 0, 0);
        acc1 = __builtin_amdgcn_mfma_f32_16x16x32_bf16(a, b1, acc1, 0, 0, 0);
      }
    }

    // ---- h contribution (k = 512..1023), agent-coherent atomic loads
    {
      const unsigned long long* hp =
          (const unsigned long long*)(ring + (size_t)slotR * (B_N * H_N) + arow * H_N + kg);
#pragma unroll 4
      for (int kk = 0; kk < 16; ++kk) {
        unsigned long long q0 = __hip_atomic_load(hp + kk * 8, __ATOMIC_RELAXED, __HIP_MEMORY_SCOPE_AGENT);
        unsigned long long q1 = __hip_atomic_load(hp + kk * 8 + 1, __ATOMIC_RELAXED, __HIP_MEMORY_SCOPE_AGENT);
        union { unsigned long long q[2]; bf16x8 v; } u;
        u.q[0] = q0; u.q[1] = q1;
        int kb = 512 + kk * 32 + kg;
        bf16x8 b0 = *(const bf16x8*)&Wl[bofs0 + (kb ^ swz)];
        bf16x8 b1 = *(const bf16x8*)&Wl[bofs1 + (kb ^ swz)];
        acc0 = __builtin_amdgcn_mfma_f32_16x16x32_bf16(u.v, b0, acc0, 0, 0, 0);
        acc1 = __builtin_amdgcn_mfma_f32_16x16x32_bf16(u.v, b1, acc1, 0, 0, 0);
      }
    }

    // ---- gate nonlinearities + cell update
    // acc0 col = l16 (f if l16<8 else i); acc1 col = 16+l16 (g if l16<8 else o)
    const bool lo = (l16 < 8);
    float hv[4];
#pragma unroll
    for (int r = 0; r < 4; ++r) {
      float m0 = acc0[r] + bias0;
      float m1 = acc1[r] + bias1;
      float p0 = __shfl_xor(m0, 8, 64);
      float p1 = __shfl_xor(m1, 8, 64);
      float fv = lo ? m0 : p0;
      float iv = lo ? p0 : m0;
      float gv = lo ? m1 : p1;
      float ov = lo ? p1 : m1;
      float f = sigf(fv), i = sigf(iv), g = tanhfast(gv), o = sigf(ov);
      float c = f * cst[r] + i * g;
      cst[r] = c;
      hv[r] = o * tanhfast(c);
    }

    // ---- write h_t: fp32 to out, packed-u32 bf16 to ring (agent atomics)
    {
      const int colg = c0 + cc;
      float* obase = out + (size_t)t * (B_N * H_N);
      unsigned short* rbase = ring + (size_t)slotW * (B_N * H_N);
#pragma unroll
      for (int r = 0; r < 4; ++r) {
        int row = 16 * w + 4 * g16 + r;
        unsigned short hb = f2bf(hv[r]);
        unsigned opp = __shfl_xor((unsigned)hb, 1, 64);
        if (lo) {
          obase[(size_t)row * H_N + colg] = hv[r];
          if ((cc & 1) == 0) {
            unsigned pack = (unsigned)hb | (opp << 16);
            __hip_atomic_store((unsigned*)(rbase + (size_t)row * H_N + colg), pack,
                               __ATOMIC_RELAXED, __HIP_MEMORY_SCOPE_AGENT);
          }
        }
      }
      if (t == T_N - 1) {
#pragma unroll
        for (int r = 0; r < 4; ++r) hT_local[r] = hv[r];
      }
    }

    // ---- global step barrier (monotonic counter; one arrive per block/step)
    if (t < T_N - 1) {
      __syncthreads();  // drains vmcnt -> all ring stores of this block complete
      if (tid == 0) {
        __hip_atomic_fetch_add(cnt, 1u, __ATOMIC_ACQ_REL, __HIP_MEMORY_SCOPE_AGENT);
        const unsigned tgt = (unsigned)(NBLK * (t + 1));
        long guard = 0;
        while (__hip_atomic_load(cnt, __ATOMIC_RELAXED, __HIP_MEMORY_SCOPE_AGENT) < tgt) {
          __builtin_amdgcn_s_sleep(8);
          if (++guard > (1l << 28)) break;  // bail-out: no deadlock-hang
        }
        __builtin_amdgcn_fence(__ATOMIC_ACQUIRE, "agent");
      }
      __syncthreads();
    }
  }

  // ---- final hT / cT
  if (l16 < 8) {
#pragma unroll
    for (int r = 0; r < 4; ++r) {
      int row = 16 * w + 4 * g16 + r;
      out[HT_OFF + (size_t)row * H_N + c0 + cc] = hT_local[r];
      out[CT_OFF + (size_t)row * H_N + c0 + cc] = cst[r];
    }
  }
}

extern "C" void kernel_launch(void* const* d_in, const int* in_sizes, int n_in,
                              void* d_out, int out_size, void* d_ws, size_t ws_size,
                              hipStream_t stream) {
  const float* X  = (const float*)d_in[0];
  const float* Wf = (const float*)d_in[1];
  const float* bF = (const float*)d_in[2];
  const float* Wi = (const float*)d_in[3];
  const float* bI = (const float*)d_in[4];
  const float* Wg = (const float*)d_in[5];
  const float* bG = (const float*)d_in[6];
  const float* Wo = (const float*)d_in[7];
  const float* bO = (const float*)d_in[8];
  float* out = (float*)d_out;

  unsigned char* ws = (unsigned char*)d_ws;
  unsigned* cnt = (unsigned*)ws;                          // 4 B @ offset 0
  unsigned short* ring = (unsigned short*)(ws + 1024);    // 2 x 64x512 bf16 = 128 KB
  const size_t xb_off = 262144;
  const size_t need_xb = xb_off + (size_t)T_N * B_N * D_N * 2;  // ~128.25 MB
  unsigned short* Xb = (ws_size >= need_xb) ? (unsigned short*)(ws + xb_off) : nullptr;

  init_ws_kernel<<<dim3(128), dim3(256), 0, stream>>>(cnt, (unsigned*)ring);
  if (Xb) {
    // convert all of X to bf16 once (parallel, off the critical path)
    xconv_kernel<<<dim3((T_N * B_N * D_N) / 8 / 256), dim3(256), 0, stream>>>(X, Xb);
  }
  lstm_kernel<<<dim3(NBLK), dim3(NTHR), 0, stream>>>(
      X, Xb, Wf, bF, Wi, bI, Wg, bG, Wo, bO, ring, cnt, out);
}

// Round 2
// 21341.177 us; speedup vs baseline: 1.0255x; 1.0255x over previous
//
#include <hip/hip_runtime.h>
#include <hip/hip_bf16.h>

// LSTM: T=2048 steps, B=64, D=512, H=512. Persistent kernel, 64 blocks x 256
// threads; block b owns hidden cols [8b,8b+8) -> 32 gate cols. W slice in LDS
// (bf16, fragment-linear layout -> conflict-free ds_read_b128). c-state in
// registers. h exchanged per step via 2-slot bf16 ring in d_ws (agent atomics).
// Grid sync: per-block flag words + 64-lane parallel poll (no contended RMW).

#define T_N 2048
#define B_N 64
#define D_N 512
#define H_N 512
#define DH_N 1024
#define NBLK 64
#define CPB 8
#define GCPB 32
#define NTHR 256

#define STACK_ELEMS ((size_t)T_N * B_N * H_N)   // 67108864
#define HT_OFF STACK_ELEMS
#define CT_OFF (STACK_ELEMS + (size_t)B_N * H_N)

typedef __attribute__((ext_vector_type(4))) float f32x4;
typedef __attribute__((ext_vector_type(8))) short bf16x8;

__device__ __forceinline__ unsigned short f2bf(float f) {
  union { __hip_bfloat16 h; unsigned short u; } u;
  u.h = __float2bfloat16(f);
  return u.u;
}

__device__ __forceinline__ float sigf(float x) { return 1.0f / (1.0f + __expf(-x)); }
__device__ __forceinline__ float tanhfast(float x) { return 1.0f - 2.0f / (__expf(2.0f * x) + 1.0f); }

// zero ws control region: [0, 262144) bytes = flags + ring + padding
__global__ void init_ws_kernel(unsigned* ws32) {
  int i = blockIdx.x * blockDim.x + threadIdx.x;
  if (i < 65536) ws32[i] = 0u;
}

__global__ void xconv_kernel(const float* __restrict__ X, unsigned short* __restrict__ Xb) {
  size_t i = ((size_t)blockIdx.x * blockDim.x + threadIdx.x) * 8;
  float4 v0 = *(const float4*)(X + i);
  float4 v1 = *(const float4*)(X + i + 4);
  bf16x8 o;
  o[0] = (short)f2bf(v0.x); o[1] = (short)f2bf(v0.y);
  o[2] = (short)f2bf(v0.z); o[3] = (short)f2bf(v0.w);
  o[4] = (short)f2bf(v1.x); o[5] = (short)f2bf(v1.y);
  o[6] = (short)f2bf(v1.z); o[7] = (short)f2bf(v1.w);
  *(bf16x8*)(Xb + i) = o;
}

__global__ __launch_bounds__(NTHR, 1) void lstm_kernel(
    const float* __restrict__ X, const unsigned short* __restrict__ Xb,
    const float* __restrict__ Wf, const float* __restrict__ bF,
    const float* __restrict__ Wi, const float* __restrict__ bI,
    const float* __restrict__ Wg, const float* __restrict__ bG,
    const float* __restrict__ Wo, const float* __restrict__ bO,
    unsigned short* __restrict__ ring, unsigned* __restrict__ flags,
    float* __restrict__ out) {
  // W in LDS, fragment-linear: for K-step kk (32 k-elems), the 64 B-fragments
  // (one per lane) of N-tile 0 live at bytes [kk*2048 + lane*16), N-tile 1 at
  // +1024. Each ds_read_b128 touches one contiguous 1KiB block: conflict-free.
  __shared__ unsigned short Wl[GCPB * DH_N];  // 64 KB

  const int tid = threadIdx.x;
  const int blk = blockIdx.x;
  const int c0 = blk * CPB;
  const int w = tid >> 6;        // wave 0..3 -> A-rows 16w..16w+15
  const int lane = tid & 63;
  const int l16 = lane & 15;
  const int g16 = lane >> 4;

  // Stage W (gate cols: 0-7=f, 8-15=i, 16-23=g, 24-31=o), fragment-linear pack:
  // element (cl, k): pos = (k>>5)*1024 + (cl>>4)*512 + ((k>>3)&3)*128 + (cl&15)*8 + (k&7)
  for (int idx = tid; idx < GCPB * DH_N; idx += NTHR) {
    int k = idx >> 5;
    int cl = idx & 31;
    const float* wsrc = (cl < 8) ? Wf : (cl < 16) ? Wi : (cl < 24) ? Wg : Wo;
    float v = wsrc[(size_t)k * H_N + c0 + (cl & 7)];
    int pos = ((k >> 5) * 1024) + ((cl >> 4) * 512) + (((k >> 3) & 3) * 128) + ((cl & 15) * 8) + (k & 7);
    Wl[pos] = f2bf(v);
  }

  const int cc = l16 & 7;
  const float bias0 = (l16 < 8) ? bF[c0 + cc] : bI[c0 + cc];
  const float bias1 = (l16 < 8) ? bG[c0 + cc] : bO[c0 + cc];
  __syncthreads();

  const int arow = 16 * w + l16;  // A row this lane feeds into mfma
  const int kg = 8 * g16;         // k sub-offset within a 32-wide K step
  const int lofs8 = lane * 8;     // u16 offset of this lane's B fragment

  float cst[4] = {0.f, 0.f, 0.f, 0.f};
  float hT_local[4] = {0.f, 0.f, 0.f, 0.f};

  for (int t = 0; t < T_N; ++t) {
    const int slotR = (t + 1) & 1;  // holds h_{t-1}
    const int slotW = t & 1;        // receives h_t
    f32x4 acc0 = {0.f, 0.f, 0.f, 0.f};
    f32x4 acc1 = {0.f, 0.f, 0.f, 0.f};

    // ---- x contribution (k = 0..511): independent of recurrence, runs
    // before the flag wait so it overlaps other blocks' tail work.
    if (Xb) {
      const unsigned short* xp = Xb + ((size_t)t * B_N + arow) * D_N + kg;
#pragma unroll 4
      for (int kk = 0; kk < 16; ++kk) {
        bf16x8 a = *(const bf16x8*)(xp + kk * 32);
        bf16x8 b0 = *(const bf16x8*)&Wl[kk * 1024 + lofs8];
        bf16x8 b1 = *(const bf16x8*)&Wl[kk * 1024 + 512 + lofs8];
        acc0 = __builtin_amdgcn_mfma_f32_16x16x32_bf16(a, b0, acc0, 0, 0, 0);
        acc1 = __builtin_amdgcn_mfma_f32_16x16x32_bf16(a, b1, acc1, 0, 0, 0);
      }
    } else {
      const float* xp = X + ((size_t)t * B_N + arow) * D_N + kg;
#pragma unroll 2
      for (int kk = 0; kk < 16; ++kk) {
        float4 v0 = *(const float4*)(xp + kk * 32);
        float4 v1 = *(const float4*)(xp + kk * 32 + 4);
        bf16x8 a;
        a[0] = (short)f2bf(v0.x); a[1] = (short)f2bf(v0.y);
        a[2] = (short)f2bf(v0.z); a[3] = (short)f2bf(v0.w);
        a[4] = (short)f2bf(v1.x); a[5] = (short)f2bf(v1.y);
        a[6] = (short)f2bf(v1.z); a[7] = (short)f2bf(v1.w);
        bf16x8 b0 = *(const bf16x8*)&Wl[kk * 1024 + lofs8];
        bf16x8 b1 = *(const bf16x8*)&Wl[kk * 1024 + 512 + lofs8];
        acc0 = __builtin_amdgcn_mfma_f32_16x16x32_bf16(a, b0, acc0, 0, 0, 0);
        acc1 = __builtin_amdgcn_mfma_f32_16x16x32_bf16(a, b1, acc1, 0, 0, 0);
      }
    }

    // ---- wait for all blocks to have published h_{t-1} (flag[b] >= t).
    // Parallel poll: lane i watches flag of block i. No RMW, no contention.
    if (t > 0) {
      if (tid < 64) {
        const unsigned tgt = (unsigned)t;
        long guard = 0;
        for (;;) {
          unsigned v = __hip_atomic_load(flags + tid * 64, __ATOMIC_RELAXED, __HIP_MEMORY_SCOPE_AGENT);
          if (__all((int)(v >= tgt))) break;
          __builtin_amdgcn_s_sleep(1);
          if (++guard > (1l << 27)) break;  // bail-out: no deadlock-hang
        }
        __builtin_amdgcn_fence(__ATOMIC_ACQUIRE, "agent");
      }
      __syncthreads();
    }

    // ---- h contribution (k = 512..1023), agent-coherent atomic loads
    {
      const unsigned long long* hp =
          (const unsigned long long*)(ring + (size_t)slotR * (B_N * H_N) + arow * H_N + kg);
#pragma unroll 4
      for (int kk = 0; kk < 16; ++kk) {
        unsigned long long q0 = __hip_atomic_load(hp + kk * 8, __ATOMIC_RELAXED, __HIP_MEMORY_SCOPE_AGENT);
        unsigned long long q1 = __hip_atomic_load(hp + kk * 8 + 1, __ATOMIC_RELAXED, __HIP_MEMORY_SCOPE_AGENT);
        union { unsigned long long q[2]; bf16x8 v; } u;
        u.q[0] = q0; u.q[1] = q1;
        bf16x8 b0 = *(const bf16x8*)&Wl[(16 + kk) * 1024 + lofs8];
        bf16x8 b1 = *(const bf16x8*)&Wl[(16 + kk) * 1024 + 512 + lofs8];
        acc0 = __builtin_amdgcn_mfma_f32_16x16x32_bf16(u.v, b0, acc0, 0, 0, 0);
        acc1 = __builtin_amdgcn_mfma_f32_16x16x32_bf16(u.v, b1, acc1, 0, 0, 0);
      }
    }

    // ---- gate nonlinearities + cell update
    // acc0 col = l16 (f if l16<8 else i); acc1 col = 16+l16 (g if l16<8 else o)
    const bool lo = (l16 < 8);
    float hv[4];
#pragma unroll
    for (int r = 0; r < 4; ++r) {
      float m0 = acc0[r] + bias0;
      float m1 = acc1[r] + bias1;
      float p0 = __shfl_xor(m0, 8, 64);
      float p1 = __shfl_xor(m1, 8, 64);
      float fv = lo ? m0 : p0;
      float iv = lo ? p0 : m0;
      float gv = lo ? m1 : p1;
      float ov = lo ? p1 : m1;
      float f = sigf(fv), i = sigf(iv), g = tanhfast(gv), o = sigf(ov);
      float c = f * cst[r] + i * g;
      cst[r] = c;
      hv[r] = o * tanhfast(c);
    }

    // ---- publish h_t to ring (packed bf16, agent atomics) — critical path
    unsigned short* rbase = ring + (size_t)slotW * (B_N * H_N);
#pragma unroll
    for (int r = 0; r < 4; ++r) {
      int row = 16 * w + 4 * g16 + r;
      unsigned short hb = f2bf(hv[r]);
      unsigned opp = __shfl_xor((unsigned)hb, 1, 64);
      if (lo && (cc & 1) == 0) {
        unsigned pack = (unsigned)hb | (opp << 16);
        __hip_atomic_store((unsigned*)(rbase + (size_t)row * H_N + c0 + cc), pack,
                           __ATOMIC_RELAXED, __HIP_MEMORY_SCOPE_AGENT);
      }
    }

    __syncthreads();  // all waves' ring stores drained (vmcnt) before flag
    if (tid == 0 && t < T_N - 1) {
      __builtin_amdgcn_fence(__ATOMIC_RELEASE, "agent");
      __hip_atomic_store(flags + blk * 64, (unsigned)(t + 1),
                         __ATOMIC_RELAXED, __HIP_MEMORY_SCOPE_AGENT);
    }

    // ---- fp32 h_t to out — AFTER flag release, off the critical path
    {
      float* obase = out + (size_t)t * (B_N * H_N);
#pragma unroll
      for (int r = 0; r < 4; ++r) {
        int row = 16 * w + 4 * g16 + r;
        if (lo) obase[(size_t)row * H_N + c0 + cc] = hv[r];
      }
      if (t == T_N - 1) {
#pragma unroll
        for (int r = 0; r < 4; ++r) hT_local[r] = hv[r];
      }
    }
  }

  // ---- final hT / cT
  if (l16 < 8) {
#pragma unroll
    for (int r = 0; r < 4; ++r) {
      int row = 16 * w + 4 * g16 + r;
      out[HT_OFF + (size_t)row * H_N + c0 + cc] = hT_local[r];
      out[CT_OFF + (size_t)row * H_N + c0 + cc] = cst[r];
    }
  }
}

extern "C" void kernel_launch(void* const* d_in, const int* in_sizes, int n_in,
                              void* d_out, int out_size, void* d_ws, size_t ws_size,
                              hipStream_t stream) {
  const float* X  = (const float*)d_in[0];
  const float* Wf = (const float*)d_in[1];
  const float* bF = (const float*)d_in[2];
  const float* Wi = (const float*)d_in[3];
  const float* bI = (const float*)d_in[4];
  const float* Wg = (const float*)d_in[5];
  const float* bG = (const float*)d_in[6];
  const float* Wo = (const float*)d_in[7];
  const float* bO = (const float*)d_in[8];
  float* out = (float*)d_out;

  unsigned char* ws = (unsigned char*)d_ws;
  unsigned* flags = (unsigned*)(ws + 1024);               // 64 flags, 256B stride
  unsigned short* ring = (unsigned short*)(ws + 32768);   // 2 x 64x512 bf16 = 128 KB
  const size_t xb_off = 262144;
  const size_t need_xb = xb_off + (size_t)T_N * B_N * D_N * 2;  // ~128.25 MB
  unsigned short* Xb = (ws_size >= need_xb) ? (unsigned short*)(ws + xb_off) : nullptr;

  init_ws_kernel<<<dim3(256), dim3(256), 0, stream>>>((unsigned*)ws);
  if (Xb) {
    xconv_kernel<<<dim3((T_N * B_N * D_N) / 8 / 256), dim3(256), 0, stream>>>(X, Xb);
  }
  lstm_kernel<<<dim3(NBLK), dim3(NTHR), 0, stream>>>(
      X, Xb, Wf, bF, Wi, bI, Wg, bG, Wo, bO, ring, flags, out);
}